// Round 5
// baseline (296.448 us; speedup 1.0000x reference)
//
#include <hip/hip_runtime.h>

#define NN 4096
#define FF 256
#define EE 65536
#define MAXDEG 64
#define MAXEPR 256
#define NCAND 2048

__device__ __forceinline__ int wred_sum(int v) {
#pragma unroll
    for (int o = 32; o >= 1; o >>= 1) v += __shfl_xor(v, o);
    return v;
}
__device__ __forceinline__ double wred_dsum(double v) {
#pragma unroll
    for (int o = 32; o >= 1; o >>= 1) v += __shfl_xor(v, o);
    return v;
}

// ---------------------------------------------------------------------------
// K1: per-row edge-id lists only
// ---------------------------------------------------------------------------
__global__ void k_scatter(const int* __restrict__ ei, int* __restrict__ ecnt,
                          int* __restrict__ elist) {
    int e = blockIdx.x * blockDim.x + threadIdx.x;
    if (e >= EE) return;
    int r = ei[e];
    int p = atomicAdd(&ecnt[r], 1);
    if (p < MAXEPR) elist[r * MAXEPR + p] = e;
}

// ---------------------------------------------------------------------------
// K2: block-per-row CSR build via dense LDS row: scatter-add (dedup), clamp,
// drop diagonal, ballot-compact. Also sq[row] (f64).
// ---------------------------------------------------------------------------
__global__ void k_build(const int* __restrict__ ei, const float* __restrict__ ew,
                        const int* __restrict__ ecnt, const int* __restrict__ elist,
                        const float* __restrict__ X,
                        unsigned short* __restrict__ ccol, float* __restrict__ cval,
                        int* __restrict__ deg, double* __restrict__ sq) {
    __shared__ float row[NN];
    __shared__ int cnt;
    const int u = blockIdx.x;
    const int tid = threadIdx.x;
    const int lane = tid & 63;
    const unsigned long long lmask = (1ull << lane) - 1ull;

    for (int i = tid; i < NN / 4; i += 256) ((float4*)row)[i] = make_float4(0.f, 0.f, 0.f, 0.f);
    if (tid == 0) cnt = 0;
    __syncthreads();

    int ne = ecnt[u]; if (ne > MAXEPR) ne = MAXEPR;
    for (int i = tid; i < ne; i += 256) {
        int e = elist[u * MAXEPR + i];
        int c = ei[EE + e];
        if (c != u) atomicAdd(&row[c], ew[e]);
    }
    __syncthreads();

    for (int i4 = tid; i4 < NN / 4; i4 += 256) {
        float4 a4 = ((float4*)row)[i4];
        float e4[4] = {a4.x, a4.y, a4.z, a4.w};
#pragma unroll
        for (int j = 0; j < 4; ++j) {
            bool nzf = (e4[j] != 0.f);
            unsigned long long m = __ballot(nzf);
            int base = 0;
            if (lane == 0 && m) base = atomicAdd(&cnt, __popcll(m));
            base = __shfl(base, 0);
            int pos = base + __popcll(m & lmask);
            if (nzf && pos < MAXDEG) {
                ccol[u * MAXDEG + pos] = (unsigned short)(i4 * 4 + j);
                cval[u * MAXDEG + pos] = fminf(e4[j], 1.f);
            }
        }
    }
    __syncthreads();
    if (tid == 0) deg[u] = cnt;

    if (tid < 64) {
        float4 x4 = ((const float4*)(X + (size_t)u * FF))[lane];
        double s = (double)x4.x * x4.x + (double)x4.y * x4.y +
                   (double)x4.z * x4.z + (double)x4.w * x4.w;
        s = wred_dsum(s);
        if (lane == 0) sq[u] = s;
    }
}

// ---------------------------------------------------------------------------
// K3: per-row main kernel (d_thres folded in)
// ---------------------------------------------------------------------------
__launch_bounds__(256, 5)
__global__ void k_main(const int* __restrict__ ei, const float* __restrict__ ew,
                       const float* __restrict__ X, const float* __restrict__ th1p,
                       const float* __restrict__ th2p,
                       const unsigned short* __restrict__ ccol,
                       const float* __restrict__ cval, const int* __restrict__ deg,
                       const int* __restrict__ ecnt, const int* __restrict__ elist,
                       const double* __restrict__ sq, float* __restrict__ out) {
    __shared__ float acc[NN];              // A2 row values (16KB)
    __shared__ float Xu[FF];               // 1KB
    __shared__ unsigned short cidx[NCAND]; // 4KB
    __shared__ float cdist[NCAND];         // 8KB
    __shared__ unsigned short Aucol[MAXDEG];
    __shared__ float Auval[MAXDEG];
    __shared__ double sd[4], sd2[4];
    __shared__ double thres_s;
    __shared__ int ncand;

    const int u = blockIdx.x;
    const int tid = threadIdx.x;
    const int lane = tid & 63;
    const int wave = tid >> 6;
    const unsigned long long lmask = (1ull << lane) - 1ull;

    const int du = deg[u];
    const int dul = min(du, MAXDEG);
    for (int i = tid; i < NN / 4; i += 256) ((float4*)acc)[i] = make_float4(0.f, 0.f, 0.f, 0.f);
    if (tid < FF / 4)
        ((float4*)Xu)[tid] = ((const float4*)(X + (size_t)u * FF))[tid];
    if (tid >= 128 && tid - 128 < dul) {
        Aucol[tid - 128] = ccol[u * MAXDEG + tid - 128];
        Auval[tid - 128] = cval[u * MAXDEG + tid - 128];
    }
    if (tid == 0) ncand = 0;
    // d_thres partials (deg[] is complete before this kernel launches)
    {
        double s = 0, s2 = 0;
        for (int i = tid; i < NN; i += 256) {
            double d = (double)deg[i];
            s += d; s2 += d * d;
        }
        s = wred_dsum(s); s2 = wred_dsum(s2);
        if (lane == 0) { sd[wave] = s; sd2[wave] = s2; }
    }
    __syncthreads();
    if (tid == 0) {
        double s = sd[0] + sd[1] + sd[2] + sd[3];
        double s2 = sd2[0] + sd2[1] + sd2[2] + sd2[3];
        double mean = s / NN;
        double var = s2 / NN - mean * mean;
        if (var < 0) var = 0;
        thres_s = mean + 2.0 * sqrt(var);   // visible to all after next barrier
    }

    // --- phase A: build A2 row. A' = A + I; acc[v] += A'[u][k]*A'[k][v] ---
    // per-lane neighbor preload kills the deg->ccol dependent-load chain
    int pcol = u; float pw = 1.f; int pdeg = dul;
    if (lane < dul) {
        pcol = Aucol[lane];
        pw = Auval[lane];
        pdeg = min(deg[pcol], MAXDEG);
    }
    for (int kk = wave; kk <= dul; kk += 4) {
        int k = (kk == dul) ? u : __shfl(pcol, kk);
        float wuk = (kk == dul) ? 1.f : __shfl(pw, kk);
        int dkl = (kk == dul) ? dul : __shfl(pdeg, kk);
        for (int j = lane; j <= dkl; j += 64) {
            int v; float wkv;
            if (j == dkl) { v = k; wkv = 1.f; }        // self term A'[k][k]=1
            else { v = ccol[k * MAXDEG + j]; wkv = cval[k * MAXDEG + j]; }
            atomicAdd(&acc[v], wuk * wkv);
        }
    }
    __syncthreads();
    if (tid == 0) acc[u] = 0.f;                        // zero diag of A2
    __syncthreads();

    // --- phase B: compact 2-hop candidates (float4 reads, ballot-aggregated) ---
    for (int i4 = tid; i4 < NN / 4; i4 += 256) {
        float4 a4 = ((float4*)acc)[i4];
        float e4[4] = {a4.x, a4.y, a4.z, a4.w};
#pragma unroll
        for (int j = 0; j < 4; ++j) {
            bool nzf = (e4[j] != 0.f);
            unsigned long long m = __ballot(nzf);
            int base = 0;
            if (lane == 0 && m) base = atomicAdd(&ncand, __popcll(m));
            base = __shfl(base, 0);
            int pos = base + __popcll(m & lmask);
            if (nzf && pos < NCAND) cidx[pos] = (unsigned short)(i4 * 4 + j);
        }
    }
    __syncthreads();
    const int Dr = ncand;
    const int Drs = min(Dr, NCAND);

    // --- phase C: distances, wave-per-candidate, 8 candidates in flight ---
    // One load instr per candidate row = 1KB contiguous (8x128B transactions)
    // vs thread-per-candidate's 256 scattered 16B transactions per row.
    const double squ = sq[u];
    const float4 b4 = ((const float4*)Xu)[lane];
    for (int cb = wave * 8; cb < Drs; cb += 32) {
        double sqv_l = 0.0;
        if (lane < 8) {
            int cl = cb + lane; cl = (cl < Drs) ? cl : (Drs - 1);
            sqv_l = sq[cidx[cl]];
        }
        double d[8];
#pragma unroll
        for (int i = 0; i < 8; ++i) {
            int ci = cb + i; ci = (ci < Drs) ? ci : (Drs - 1);
            int v = cidx[ci];
            float4 a = ((const float4*)(X + (size_t)v * FF))[lane];
            d[i] = (double)a.x * b4.x + (double)a.y * b4.y +
                   (double)a.z * b4.z + (double)a.w * b4.w;
        }
#pragma unroll
        for (int i = 0; i < 8; ++i) {
#pragma unroll
            for (int o = 32; o >= 1; o >>= 1) d[i] += __shfl_xor(d[i], o);
        }
#pragma unroll
        for (int i = 0; i < 8; ++i) {
            if (lane == i && cb + i < Drs)
                cdist[cb + i] = (float)(squ + sqv_l - 2.0 * d[i]);
        }
    }
    __syncthreads();

    // --- phase D: per-edge output, one wave per edge ---
    const int D = du;
    const bool highD = ((double)D > thres_s);
    const int nz = Dr - 2 * D;                         // nz_sel
    const float th1 = th1p[0], th2 = th2p[0];
    int ne = ecnt[u]; if (ne > MAXEPR) ne = MAXEPR;
    for (int idx = wave; idx < ne; idx += 4) {
        int e = elist[u * MAXEPR + idx];
        int v = ei[EE + e];                            // wave-uniform
        float w = ew[e];
        float a2v = acc[v];
        // av = A[u][v] via LDS CSR row scan (ballot+shfl)
        float avl = 0.f;
        bool hit = false;
        for (int t = lane; t < dul; t += 64)
            if ((int)Aucol[t] == v) { avl = Auval[t]; hit = true; }
        unsigned long long hm = __ballot(hit);
        float av = hm ? __shfl(avl, (int)__builtin_ctzll(hm)) : 0.f;
        float adj;
        if (highD) {
            adj = (av != 0.f) ? (a2v - av) : 0.f;      // Z_high = (A==0)
        } else if (nz < 0) {
            adj = a2v - av;                             // nosparse: Z = false
        } else if (nz == 0) {
            adj = 0.f;                                  // all nbrs masked
        } else if (a2v == 0.f) {
            adj = 0.f;                                  // not a 2-hop nbr (A subset A2)
        } else {
            // dv lookup among candidates (ballot+shfl)
            float dvl = 0.f; bool fnd = false;
            for (int c = lane; c < Drs; c += 64)
                if ((int)cidx[c] == v) { dvl = cdist[c]; fnd = true; }
            unsigned long long fm = __ballot(fnd);
            float dv = __shfl(dvl, (int)__builtin_ctzll(fm));
            // stable descending rank of v among candidates
            int cnt = 0;
            for (int c = lane; c < Drs; c += 64) {
                float cd = cdist[c];
                int ci = cidx[c];
                cnt += (cd > dv || (cd == dv && ci < v)) ? 1 : 0;
            }
            cnt = wred_sum(cnt);
            adj = (cnt < nz) ? 0.f : (a2v - av);
        }
        if (lane == 0) out[e] = fmaxf(0.f, fmaf(th1, w, th2 * adj));
    }
}

// ---------------------------------------------------------------------------
extern "C" void kernel_launch(void* const* d_in, const int* in_sizes, int n_in,
                              void* d_out, int out_size, void* d_ws, size_t ws_size,
                              hipStream_t stream) {
    const int* ei = (const int*)d_in[0];
    const float* ew = (const float*)d_in[1];
    const float* X = (const float*)d_in[2];
    const float* th1 = (const float*)d_in[3];
    const float* th2 = (const float*)d_in[4];
    float* out = (float*)d_out;

    char* ws = (char*)d_ws;
    size_t off = 0;
    unsigned short* ccol = (unsigned short*)(ws + off); off += (size_t)NN * MAXDEG * 2;
    float* cval = (float*)(ws + off);         off += (size_t)NN * MAXDEG * 4;
    int* deg = (int*)(ws + off);              off += (size_t)NN * 4;
    int* ecnt = (int*)(ws + off);             off += (size_t)NN * 4;
    double* sq = (double*)(ws + off);         off += (size_t)NN * 8;
    int* elist = (int*)(ws + off);            off += (size_t)NN * MAXEPR * 4;

    hipMemsetAsync(ecnt, 0, (size_t)NN * 4, stream);

    k_scatter<<<EE / 256, 256, 0, stream>>>(ei, ecnt, elist);
    k_build<<<NN, 256, 0, stream>>>(ei, ew, ecnt, elist, X, ccol, cval, deg, sq);
    k_main<<<NN, 256, 0, stream>>>(ei, ew, X, th1, th2, ccol, cval, deg,
                                   ecnt, elist, sq, out);
}

// Round 7
// 272.059 us; speedup vs baseline: 1.0896x; 1.0896x over previous
//
#include <hip/hip_runtime.h>

#define NN 4096
#define FF 256
#define EE 65536
#define MAXDEG 64
#define MAXEPR 256
#define NCAND 1024

__device__ __forceinline__ int wred_sum(int v) {
#pragma unroll
    for (int o = 32; o >= 1; o >>= 1) v += __shfl_xor(v, o);
    return v;
}
__device__ __forceinline__ double wred_dsum(double v) {
#pragma unroll
    for (int o = 32; o >= 1; o >>= 1) v += __shfl_xor(v, o);
    return v;
}

// ---------------------------------------------------------------------------
// K1: per-row edge-id lists
// ---------------------------------------------------------------------------
__global__ void k_scatter(const int* __restrict__ ei, int* __restrict__ ecnt,
                          int* __restrict__ elist) {
    int e = blockIdx.x * blockDim.x + threadIdx.x;
    if (e >= EE) return;
    int r = ei[e];
    int p = atomicAdd(&ecnt[r], 1);
    if (p < MAXEPR) elist[r * MAXEPR + p] = e;
}

// ---------------------------------------------------------------------------
// K2: sparse CSR build, one 64-thread block per row. Zero only touched LDS
// slots, scatter-add, then dedup via atomicExch claim. Also sq[row] (f64).
// ---------------------------------------------------------------------------
__global__ void k_build(const int* __restrict__ ei, const float* __restrict__ ew,
                        const int* __restrict__ ecnt, const int* __restrict__ elist,
                        const float* __restrict__ X,
                        unsigned short* __restrict__ ccol, float* __restrict__ cval,
                        int* __restrict__ deg, double* __restrict__ sq) {
    __shared__ float row[NN];          // uninitialized; only touched slots used
    __shared__ int cnt;
    const int u = blockIdx.x;
    const int lane = threadIdx.x;      // 64 threads
    if (lane == 0) cnt = 0;

    int ne = ecnt[u]; if (ne > MAXEPR) ne = MAXEPR;
    // pass 1: zero touched columns
    for (int i = lane; i < ne; i += 64) {
        int c = ei[EE + elist[u * MAXEPR + i]];
        if (c != u) row[c] = 0.f;
    }
    __syncthreads();
    // pass 2: accumulate duplicate weights
    for (int i = lane; i < ne; i += 64) {
        int e = elist[u * MAXEPR + i];
        int c = ei[EE + e];
        if (c != u) atomicAdd(&row[c], ew[e]);
    }
    __syncthreads();
    // pass 3: claim each unique column exactly once
    for (int i = lane; i < ne; i += 64) {
        int c = ei[EE + elist[u * MAXEPR + i]];
        if (c != u) {
            float w = atomicExch(&row[c], 0.f);
            if (w != 0.f) {
                int p = atomicAdd(&cnt, 1);
                if (p < MAXDEG) {
                    ccol[u * MAXDEG + p] = (unsigned short)c;
                    cval[u * MAXDEG + p] = fminf(w, 1.f);
                }
            }
        }
    }
    __syncthreads();
    if (lane == 0) deg[u] = cnt;

    // sq[u]
    float4 x4 = ((const float4*)(X + (size_t)u * FF))[lane];
    double s = (double)x4.x * x4.x + (double)x4.y * x4.y +
               (double)x4.z * x4.z + (double)x4.w * x4.w;
    s = wred_dsum(s);
    if (lane == 0) sq[u] = s;
}

// ---------------------------------------------------------------------------
// K3: d_thres = mean(deg) + 2*std(deg), single block
// ---------------------------------------------------------------------------
__global__ void k_stats(const int* __restrict__ deg, double* __restrict__ thres) {
    __shared__ double sd[256], sd2[256];
    int t = threadIdx.x;
    double s = 0, s2 = 0;
    for (int i = t; i < NN; i += 256) {
        double d = (double)deg[i];
        s += d; s2 += d * d;
    }
    sd[t] = s; sd2[t] = s2;
    __syncthreads();
    for (int o = 128; o >= 1; o >>= 1) {
        if (t < o) { sd[t] += sd[t + o]; sd2[t] += sd2[t + o]; }
        __syncthreads();
    }
    if (t == 0) {
        double mean = sd[0] / NN;
        double var = sd2[0] / NN - mean * mean;
        if (var < 0) var = 0;
        thres[0] = mean + 2.0 * sqrt(var);
    }
}

// ---------------------------------------------------------------------------
// K4: A2-row build + candidate compaction + non-rank outputs.
// Rank-case rows: store cidx list, Dr, nz, per-edge (a2v-av); k_dist finishes.
// ---------------------------------------------------------------------------
__launch_bounds__(256, 8)
__global__ void k_a2(const int* __restrict__ ei, const float* __restrict__ ew,
                     const float* __restrict__ th1p, const float* __restrict__ th2p,
                     const unsigned short* __restrict__ ccol,
                     const float* __restrict__ cval, const int* __restrict__ deg,
                     const int* __restrict__ ecnt, const int* __restrict__ elist,
                     const double* __restrict__ thresp,
                     unsigned short* __restrict__ cidx_g, int* __restrict__ drg,
                     int* __restrict__ nzg, float* __restrict__ eadj,
                     float* __restrict__ out) {
    __shared__ float acc[NN];              // 16KB
    __shared__ unsigned short Aucol[MAXDEG];
    __shared__ float Auval[MAXDEG];
    __shared__ int ncand;

    const int u = blockIdx.x;
    const int tid = threadIdx.x;
    const int lane = tid & 63;
    const int wave = tid >> 6;
    const unsigned long long lmask = (1ull << lane) - 1ull;

    const int du = deg[u];
    const int dul = min(du, MAXDEG);
    for (int i = tid; i < NN / 4; i += 256)
        ((float4*)acc)[i] = make_float4(0.f, 0.f, 0.f, 0.f);
    if (tid < dul) {
        Aucol[tid] = ccol[u * MAXDEG + tid];
        Auval[tid] = cval[u * MAXDEG + tid];
    }
    if (tid == 0) ncand = 0;
    __syncthreads();

    // phase A: acc[v] += A'[u][k] * A'[k][v], A' = A + I
    for (int kk = wave; kk <= dul; kk += 4) {
        int k; float wuk;
        if (kk == dul) { k = u; wuk = 1.f; }
        else { k = Aucol[kk]; wuk = Auval[kk]; }
        int dkl = min(deg[k], MAXDEG);
        for (int j = lane; j <= dkl; j += 64) {
            int v; float wkv;
            if (j == dkl) { v = k; wkv = 1.f; }
            else { v = ccol[k * MAXDEG + j]; wkv = cval[k * MAXDEG + j]; }
            atomicAdd(&acc[v], wuk * wkv);
        }
    }
    __syncthreads();
    if (tid == 0) acc[u] = 0.f;
    __syncthreads();

    // phase B: compact candidates to GLOBAL cidx_g
    for (int i4 = tid; i4 < NN / 4; i4 += 256) {
        float4 a4 = ((float4*)acc)[i4];
        float e4[4] = {a4.x, a4.y, a4.z, a4.w};
#pragma unroll
        for (int j = 0; j < 4; ++j) {
            bool nzf = (e4[j] != 0.f);
            unsigned long long m = __ballot(nzf);
            int base = 0;
            if (lane == 0 && m) base = atomicAdd(&ncand, __popcll(m));
            base = __shfl(base, 0);
            int pos = base + __popcll(m & lmask);
            if (nzf && pos < NCAND) cidx_g[u * NCAND + pos] = (unsigned short)(i4 * 4 + j);
        }
    }
    __syncthreads();
    const int Dr = ncand;

    // branch select
    const bool highD = ((double)du > thresp[0]);
    const int nz = Dr - 2 * du;
    const bool rankcase = (!highD) && (nz > 0);
    const float th1 = th1p[0], th2 = th2p[0];
    if (tid == 0) {
        drg[u] = min(Dr, NCAND);
        nzg[u] = rankcase ? nz : 0;
    }

    // per-edge: finalize non-rank rows; stash a2v-av for rank rows
    int ne = ecnt[u]; if (ne > MAXEPR) ne = MAXEPR;
    for (int idx = wave; idx < ne; idx += 4) {
        int e = elist[u * MAXEPR + idx];
        int v = ei[EE + e];                            // wave-uniform
        float w = ew[e];
        float a2v = acc[v];
        // av = A[u][v] via LDS CSR scan
        float avl = 0.f; bool hit = false;
        for (int t = lane; t < dul; t += 64)
            if ((int)Aucol[t] == v) { avl = Auval[t]; hit = true; }
        unsigned long long hm = __ballot(hit);
        float av = hm ? __shfl(avl, (int)__builtin_ctzll(hm)) : 0.f;
        if (rankcase) {
            if (lane == 0) eadj[u * MAXEPR + idx] = a2v - av;
        } else {
            float adj;
            if (highD)       adj = (av != 0.f) ? (a2v - av) : 0.f;
            else if (nz < 0) adj = a2v - av;
            else             adj = 0.f;                // nz == 0
            if (lane == 0) out[e] = fmaxf(0.f, fmaf(th1, w, th2 * adj));
        }
    }
}

// ---------------------------------------------------------------------------
// K5: distances + rank for rank-case rows only. Slim LDS -> full occupancy.
// ---------------------------------------------------------------------------
__launch_bounds__(256, 8)
__global__ void k_dist(const int* __restrict__ ei, const float* __restrict__ ew,
                       const float* __restrict__ X, const float* __restrict__ th1p,
                       const float* __restrict__ th2p,
                       const int* __restrict__ ecnt, const int* __restrict__ elist,
                       const double* __restrict__ sq,
                       const unsigned short* __restrict__ cidx_g,
                       const int* __restrict__ drg, const int* __restrict__ nzg,
                       const float* __restrict__ eadj, float* __restrict__ out) {
    __shared__ float Xu[FF];               // 1KB
    __shared__ unsigned short cidx[NCAND]; // 2KB
    __shared__ float cdist[NCAND];         // 4KB

    const int u = blockIdx.x;
    const int nz = nzg[u];
    if (nz <= 0) return;                   // non-rank rows fully handled by k_a2
    const int tid = threadIdx.x;
    const int lane = tid & 63;
    const int wave = tid >> 6;

    const int Drs = drg[u];
    if (tid < FF / 4)
        ((float4*)Xu)[tid] = ((const float4*)(X + (size_t)u * FF))[tid];
    for (int i = tid; i < Drs; i += 256) cidx[i] = cidx_g[u * NCAND + i];
    __syncthreads();

    // distances: one candidate per thread, 2-chain f64 (proven 44-VGPR form)
    const double squ = sq[u];
    for (int c = tid; c < Drs; c += 256) {
        int v = cidx[c];
        const float4* __restrict__ Xv = (const float4*)(X + (size_t)v * FF);
        double sqv = sq[v];
        double s0 = 0.0, s1 = 0.0;
#pragma unroll 4
        for (int f = 0; f < FF / 4; f += 2) {
            float4 a = Xv[f];
            float4 b = ((const float4*)Xu)[f];
            s0 += (double)a.x * b.x + (double)a.y * b.y +
                  (double)a.z * b.z + (double)a.w * b.w;
            float4 p = Xv[f + 1];
            float4 q = ((const float4*)Xu)[f + 1];
            s1 += (double)p.x * q.x + (double)p.y * q.y +
                  (double)p.z * q.z + (double)p.w * q.w;
        }
        cdist[c] = (float)(squ + sqv - 2.0 * (s0 + s1));
    }
    __syncthreads();

    // per-edge: one wave per edge; stable descending rank of v
    const float th1 = th1p[0], th2 = th2p[0];
    int ne = ecnt[u]; if (ne > MAXEPR) ne = MAXEPR;
    for (int idx = wave; idx < ne; idx += 4) {
        int e = elist[u * MAXEPR + idx];
        int v = ei[EE + e];                            // wave-uniform
        float w = ew[e];
        // dv lookup
        float dvl = 0.f; bool fnd = false;
        for (int c = lane; c < Drs; c += 64)
            if ((int)cidx[c] == v) { dvl = cdist[c]; fnd = true; }
        unsigned long long fm = __ballot(fnd);
        float dv = __shfl(dvl, (int)__builtin_ctzll(fm));
        // rank count
        int cnt = 0;
        for (int c = lane; c < Drs; c += 64) {
            float cd = cdist[c];
            int ci = cidx[c];
            cnt += (cd > dv || (cd == dv && ci < v)) ? 1 : 0;
        }
        cnt = wred_sum(cnt);
        float adj = (cnt < nz) ? 0.f : eadj[u * MAXEPR + idx];
        if (lane == 0) out[e] = fmaxf(0.f, fmaf(th1, w, th2 * adj));
    }
}

// ---------------------------------------------------------------------------
extern "C" void kernel_launch(void* const* d_in, const int* in_sizes, int n_in,
                              void* d_out, int out_size, void* d_ws, size_t ws_size,
                              hipStream_t stream) {
    const int* ei = (const int*)d_in[0];
    const float* ew = (const float*)d_in[1];
    const float* X = (const float*)d_in[2];
    const float* th1 = (const float*)d_in[3];
    const float* th2 = (const float*)d_in[4];
    float* out = (float*)d_out;

    char* ws = (char*)d_ws;
    size_t off = 0;
    unsigned short* ccol = (unsigned short*)(ws + off); off += (size_t)NN * MAXDEG * 2;
    float* cval = (float*)(ws + off);          off += (size_t)NN * MAXDEG * 4;
    int* deg = (int*)(ws + off);               off += (size_t)NN * 4;
    int* ecnt = (int*)(ws + off);              off += (size_t)NN * 4;
    double* sq = (double*)(ws + off);          off += (size_t)NN * 8;
    double* thres = (double*)(ws + off);       off += 256;
    int* elist = (int*)(ws + off);             off += (size_t)NN * MAXEPR * 4;
    unsigned short* cidx_g = (unsigned short*)(ws + off); off += (size_t)NN * NCAND * 2;
    int* drg = (int*)(ws + off);               off += (size_t)NN * 4;
    int* nzg = (int*)(ws + off);               off += (size_t)NN * 4;
    float* eadj = (float*)(ws + off);          off += (size_t)NN * MAXEPR * 4;

    hipMemsetAsync(ecnt, 0, (size_t)NN * 4, stream);

    k_scatter<<<EE / 256, 256, 0, stream>>>(ei, ecnt, elist);
    k_build<<<NN, 64, 0, stream>>>(ei, ew, ecnt, elist, X, ccol, cval, deg, sq);
    k_stats<<<1, 256, 0, stream>>>(deg, thres);
    k_a2<<<NN, 256, 0, stream>>>(ei, ew, th1, th2, ccol, cval, deg, ecnt, elist,
                                 thres, cidx_g, drg, nzg, eadj, out);
    k_dist<<<NN, 256, 0, stream>>>(ei, ew, X, th1, th2, ecnt, elist, sq,
                                   cidx_g, drg, nzg, eadj, out);
}